// Round 8
// baseline (338.558 us; speedup 1.0000x reference)
//
#include <hip/hip_runtime.h>
#include <hip/hip_bf16.h>

// AlignmentContrastiveLoss on MI355X.
// Pipeline:
//   K1 normalize_pack: fp32 L2-normalize rows of im_set/s_seq, drop CLS/special
//      tokens, cast to bf16. Both packed DENSE: im' [256][36][1024],
//      s' [256][30][1024].
//   K2 gemm_scores: bf16 MFMA GEMM per block: M=144 (4 images x 36),
//      N=240 (8 sentences x 30), K=1024. 4 waves, each owns 4 N-tiles x 9
//      M-tiles. T3+T4 pipeline: BK=32 -> 32 K-SLICES (R6/R7 bug: loop ran 16
//      slices = half of K -> deterministic absmax 88), TRIPLE-buffered LDS
//      (3 x 24 KB), depth-2 prefetch, per-iter {vmcnt(6); s_barrier; stage
//      k+2; MFMA} -- vmcnt never drained to 0 in the main loop.
//      Sync points fenced per rule #18: sched_barrier(0) on both sides of
//      {s_waitcnt vmcnt(N); s_barrier} (raw s_barrier is not a compiler
//      memory fence).
//      LDS geometry: 128-B lines (two 64-B row-slices paired), XOR slot
//      swizzle phys = logical ^ (line&7) -- the R1-R3 geometry measured at
//      ZERO bank conflicts (64-B-row geometry measured 1.34e7 regardless of
//      swizzle). Both-sides rule: inverse-swizzled per-lane global source +
//      swizzled ds_read; LDS DMA dest stays linear.
//   K3 loss_partial + loss_final: contrastive loss, 64-block parallel.

typedef __attribute__((ext_vector_type(8))) short bf16x8;
typedef __attribute__((ext_vector_type(4))) float f32x4;

#define NB   256
#define DIM  1024
#define LI   36     // valid image regions (dense pack stride)
#define LS   30     // valid words (dense pack stride)
#define MT   9      // M-tiles per block (144 rows)
#define NT   15     // N-tiles per block (240 rows)
#define BUFB 24576  // bytes per LDS buffer: A 9 KB + B 15 KB (BK=32)
#define BOFF 9216   // B region byte offset within a buffer
#define NSLICE 32   // K / BK = 1024 / 32

// Fenced pipeline sync: leading sched_barrier stops prior ds_reads sinking
// below; trailing one stops this iter's ds_reads / staging hoisting above
// the s_barrier.
#define PIPE_SYNC(N) do { \
    __builtin_amdgcn_sched_barrier(0); \
    asm volatile("s_waitcnt vmcnt(" #N ")" ::: "memory"); \
    __builtin_amdgcn_s_barrier(); \
    __builtin_amdgcn_sched_barrier(0); \
} while (0)

static __device__ inline ushort f2bf(float x) {
    union { __hip_bfloat16 h; ushort u; } cvt;
    cvt.h = __float2bfloat16(x);
    return cvt.u;
}

static __device__ __forceinline__ void gload_lds16(const void* g, void* l) {
    __builtin_amdgcn_global_load_lds(
        (const __attribute__((address_space(1))) void*)g,
        (__attribute__((address_space(3))) void*)l, 16, 0, 0);
}

// One wave per output row; every row is a real (valid) row.
__global__ __launch_bounds__(256) void normalize_pack(
    const float* __restrict__ im, const float* __restrict__ sq,
    short* __restrict__ imp, short* __restrict__ sp)
{
    const int gw   = (blockIdx.x * 256 + threadIdx.x) >> 6;
    const int lane = threadIdx.x & 63;
    const int NIM  = NB * LI;   // 9216 dense image rows

    const float* src;
    short* dst;
    if (gw < NIM) {
        int b = gw / LI, i = gw - b * LI;
        dst = imp + (size_t)gw * DIM;
        src = im + ((size_t)b * 37 + i + 1) * DIM;   // drop CLS region 0
    } else {
        int g2 = gw - NIM;
        int b = g2 / LS, j = g2 - b * LS;
        dst = sp + (size_t)g2 * DIM;
        src = sq + ((size_t)b * 33 + j + 1) * DIM;   // rows 1..30 of 33
    }

    const float4* s4 = (const float4*)src;
    float4 v[4];
    float ss = 0.f;
    #pragma unroll
    for (int t = 0; t < 4; ++t) {
        float4 x = s4[lane + 64 * t];
        v[t] = x;
        ss += x.x * x.x + x.y * x.y + x.z * x.z + x.w * x.w;
    }
    #pragma unroll
    for (int o = 32; o >= 1; o >>= 1) ss += __shfl_xor(ss, o, 64);
    float scale = 1.0f / fmaxf(sqrtf(ss), 1e-12f);
    ushort4* d4 = (ushort4*)dst;
    #pragma unroll
    for (int t = 0; t < 4; ++t) {
        float4 x = v[t];
        ushort4 o;
        o.x = f2bf(x.x * scale);
        o.y = f2bf(x.y * scale);
        o.z = f2bf(x.z * scale);
        o.w = f2bf(x.w * scale);
        d4[lane + 64 * t] = o;
    }
}

// Block: 256 threads = 4 waves. blockIdx.x -> 4 images (144 dense rows),
// blockIdx.y -> 8 sentences (240 dense rows). Wave w owns N-tiles 4w..4w+3
// (wave 3: tiles 12..14), all 9 M-tiles.
//
// LDS buffer layout (per 24 KB buffer, BK=32):
//   A: lines 0..71   (line L holds rows 2L, 2L+1 of the 144)    bytes 0..9215
//   B: lines 0..119  (rows 2L, 2L+1 of the 240)                 bytes 9216..
//   Line = 128 B = 8 slots of 16 B. Slot swizzle: phys = logical ^ (line&7),
//   logical slot s = (row&1)*4 + chunk  (chunk = 16B quarter of the row's
//   64-B k-slice). Bank index depends only on phys slot -> each
//   8-consecutive-lane b128 group covers 8 distinct slots = all 32 banks
//   (verified for reads and for the linear DMA writes).
// Staging: one DMA instr = 1 KB = 8 lines = 16 rows. Lane i -> LDS linear
//   (line i>>3, phys i&7); logical s_i = (i&7)^(i>>3); global row =
//   r0 + 2*(i>>3) + (s_i>>2), byte (s_i&3)*16 within the 64-B k-slice.
// Read: row R = 16*tile + l15, chunk q -> line 8*tile + (l15>>1),
//   phys = ((l15&1)*4 + q) ^ ((l15>>1)&7) -- per-lane constant.
__global__ __launch_bounds__(256, 2) void gemm_scores(
    const short* __restrict__ imp, const short* __restrict__ sp,
    const int* __restrict__ im_len, const int* __restrict__ s_len,
    float* __restrict__ scores)
{
    __shared__ __align__(1024) char lds[3 * BUFB];   // 72 KB triple buffer
    __shared__ float sred[4][4][3];                  // [wave][img][sent-slot]

    const int tid  = threadIdx.x;
    const int wave = tid >> 6;
    const int lane = tid & 63;
    const int q    = lane >> 4;
    const int l15  = lane & 15;
    const int b0   = blockIdx.x * 4;
    const int c0   = blockIdx.y * 8;

    f32x4 acc[MT][4];
    #pragma unroll
    for (int mt = 0; mt < MT; ++mt)
        #pragma unroll
        for (int t = 0; t < 4; ++t)
            acc[mt][t] = (f32x4){0.f, 0.f, 0.f, 0.f};

    // ---- staging constants: 24 chunks/slice (A 0..8, B 9..23), 6/wave ----
    const int i8 = lane >> 3;          // line within the 8-line chunk
    const int ph = lane & 7;           // phys slot (linear LDS dest)
    const int sl = ph ^ i8;            // logical slot
    const int pr = sl >> 2;            // row parity
    const int ch = sl & 3;             // 16-B chunk within the 64-B k-slice
    const int off_lane = (2 * i8 + pr) * 2048 + ch * 16;

    const char* baseA = (const char*)imp + (size_t)(b0 * LI) * 2048;
    const char* baseB = (const char*)sp  + (size_t)(c0 * LS) * 2048;

    const char* g6[6];
    int l6[6];
    #pragma unroll
    for (int j = 0; j < 6; ++j) {
        const int cid = wave + 4 * j;            // 0..23
        if (j < 2) {                             // cid <= 7 -> A
            g6[j] = baseA + cid * 32768 + off_lane;
            l6[j] = cid * 1024;
        } else if (j > 2) {                      // cid >= 12 -> B
            g6[j] = baseB + (cid - 9) * 32768 + off_lane;
            l6[j] = BOFF + (cid - 9) * 1024;
        } else {                                 // cid = 8..11: A for wave 0
            if (wave == 0) { g6[j] = baseA + 8 * 32768 + off_lane;        l6[j] = 8 * 1024; }
            else           { g6[j] = baseB + (cid - 9) * 32768 + off_lane; l6[j] = BOFF + (cid - 9) * 1024; }
        }
    }

    // Read-side swizzled slot byte offset (per-lane constant, A and B).
    const int cs2 = (((l15 & 1) * 4 + q) ^ ((l15 >> 1) & 7)) * 16;
    const int lhalf = l15 >> 1;

    auto compute = [&](const char* buf) {
        bf16x8 bfr[4];
        #pragma unroll
        for (int t = 0; t < 4; ++t) {
            const int nt = wave * 4 + t;
            if (nt < NT)   // wave-uniform
                bfr[t] = *(const bf16x8*)(buf + BOFF + (8 * nt + lhalf) * 128 + cs2);
        }
        __builtin_amdgcn_s_setprio(1);
        #pragma unroll
        for (int mt = 0; mt < MT; ++mt) {
            bf16x8 af = *(const bf16x8*)(buf + (8 * mt + lhalf) * 128 + cs2);
            #pragma unroll
            for (int t = 0; t < 4; ++t)
                if (wave * 4 + t < NT)
                    acc[mt][t] = __builtin_amdgcn_mfma_f32_16x16x32_bf16(
                        af, bfr[t], acc[mt][t], 0, 0, 0);
        }
        __builtin_amdgcn_s_setprio(0);
    };

    // ---- prologue: stage slices 0 and 1 (6 DMA each, per wave) ----
    #pragma unroll
    for (int j = 0; j < 6; ++j) gload_lds16(g6[j], lds + l6[j]);
    #pragma unroll
    for (int j = 0; j < 6; ++j) gload_lds16(g6[j] + 64, lds + BUFB + l6[j]);

    // ---- main loop: 32 slices of K=32; vmcnt never drained to 0 ----
    // Slice k lives in buf k%3; iter kk computes slice kk, stages slice kk+2.
    int cur = 0;
    #pragma unroll 1
    for (int kk = 0; kk < NSLICE - 2; ++kk) {
        PIPE_SYNC(6);                                     // slice kk landed
        const int nb = (cur + 2 >= 3) ? cur - 1 : cur + 2;   // (kk+2)%3
        #pragma unroll
        for (int j = 0; j < 6; ++j)
            gload_lds16(g6[j] + (kk + 2) * 64, lds + nb * BUFB + l6[j]);
        compute(lds + cur * BUFB);
        cur = (cur == 2) ? 0 : cur + 1;
    }
    PIPE_SYNC(6);                                         // slice 30 landed
    compute(lds + cur * BUFB);
    cur = (cur == 2) ? 0 : cur + 1;
    PIPE_SYNC(0);                                         // slice 31 landed
    compute(lds + cur * BUFB);

    // ---- Fused epilogue ----
    // C/D layout: lane holds col = l15, row = q*4 + r.
    // Packed A row g = mt*16 + q*4 + r; image = (4*mt+q)/9, region = g - 36*image.
    // Packed B col = nt*16 + l15; sentence sidx = col/30, word j = col - 30*sidx.
    int il[4];
    #pragma unroll
    for (int bb = 0; bb < 4; ++bb) il[bb] = im_len[b0 + bb] - 1;   // in [9, 36]

    // Wave w covers cols [64w, 64w+64) -> up to 3 sentences, base (64w)/30.
    const int sbase = (64 * wave) / 30;
    float part[4][3] = {{0.f,0.f,0.f},{0.f,0.f,0.f},{0.f,0.f,0.f},{0.f,0.f,0.f}};

    #pragma unroll
    for (int t = 0; t < 4; ++t) {
        const int nt = wave * 4 + t;
        if (nt >= NT) continue;                     // wave-uniform
        const int col  = nt * 16 + l15;             // 0..239
        const int sidx = col / 30;                  // per-lane sentence
        const int j    = col - 30 * sidx;           // word index
        const int sl2  = s_len[c0 + sidx] - 3;      // valid words, in [5, 30]
        const bool jv  = (j < sl2);
        const int s_begin = (nt * 16) / 30;         // wave-uniform
        const int s_end   = (nt * 16 + 15) / 30;

        #pragma unroll
        for (int bb = 0; bb < 4; ++bb) {
            const int ilb = il[bb];
            float m = -3.4e38f;
            #pragma unroll
            for (int mt = 0; mt < MT; ++mt) {
                const int im_lo = (4 * mt) / 9;          // compile-time
                const int im_hi = (4 * mt + 3) / 9;      // compile-time
                const int thr   = 9 * im_hi - 4 * mt;    // q >= thr -> im_hi
                #pragma unroll
                for (int r = 0; r < 4; ++r) {
                    const float v = acc[mt][t][r];
                    const int base = mt * 16 + q * 4 + r;
                    if (im_lo == im_hi) {
                        if (im_lo == bb) {
                            const int i = base - 36 * bb;
                            if (i < ilb) m = fmaxf(m, v);
                        }
                    } else {
                        const bool hi = (q >= thr);
                        if (!hi && im_lo == bb) {
                            const int i = base - 36 * bb;
                            if (i < ilb) m = fmaxf(m, v);
                        } else if (hi && im_hi == bb) {
                            const int i = base - 36 * bb;
                            if (i < ilb) m = fmaxf(m, v);
                        }
                    }
                }
            }
            // combine the 4 row-quads -> full max over image bb's regions
            m = fmaxf(m, __shfl_xor(m, 16, 64));
            m = fmaxf(m, __shfl_xor(m, 32, 64));
            // masked (zeroed) rows participate in the max only when il < 36
            if (ilb < LI) m = fmaxf(m, 0.f);
            const float c = (q == 0 && jv) ? m : 0.f;   // count each col once
            #pragma unroll
            for (int slot = 0; slot < 3; ++slot) {
                const int s = sbase + slot;
                if (s >= s_begin && s <= s_end) {        // wave-uniform
                    float v = (sidx == s) ? c : 0.f;
                    #pragma unroll
                    for (int off = 32; off >= 1; off >>= 1) v += __shfl_xor(v, off, 64);
                    part[bb][slot] += v;
                }
            }
        }
    }

    if (lane == 0) {
        #pragma unroll
        for (int bb = 0; bb < 4; ++bb)
            #pragma unroll
            for (int slot = 0; slot < 3; ++slot)
                sred[wave][bb][slot] = part[bb][slot];
    }
    __syncthreads();
    // 32 score cells: tid -> (bb = tid>>3, s = tid&7); sentence s gathers from
    // the waves whose 64-col window overlaps cols [30s, 30s+30).
    if (tid < 32) {
        const int bb = tid >> 3, s = tid & 7;
        float v = 0.f;
        #pragma unroll
        for (int w = 0; w < 4; ++w) {
            const int slot = s - (64 * w) / 30;
            if (slot >= 0 && slot < 3) v += sred[w][bb][slot];
        }
        scores[(b0 + bb) * NB + c0 + s] = v;
    }
}

// 64 blocks x 4 waves; wave handles row/col t of the score matrix.
__global__ __launch_bounds__(256) void loss_partial(
    const float* __restrict__ sc, float* __restrict__ partial)
{
    const int wave = threadIdx.x >> 6, lane = threadIdx.x & 63;
    const int t = blockIdx.x * 4 + wave;
    const float dt = sc[t * (NB + 1)];
    float rowmax = 0.f, colmax = 0.f;
    #pragma unroll
    for (int p = 0; p < 4; ++p) {
        const int k = lane + 64 * p;
        const float r = sc[t * NB + k];
        const float c = sc[k * NB + t];
        if (k != t) {
            rowmax = fmaxf(rowmax, 0.2f + r - dt);
            colmax = fmaxf(colmax, 0.2f + c - dt);
        }
    }
    #pragma unroll
    for (int o = 32; o >= 1; o >>= 1) {
        rowmax = fmaxf(rowmax, __shfl_xor(rowmax, o, 64));
        colmax = fmaxf(colmax, __shfl_xor(colmax, o, 64));
    }
    if (lane == 0) partial[t] = fmaxf(rowmax, 0.f) + fmaxf(colmax, 0.f);
}

__global__ __launch_bounds__(256) void loss_final(
    const float* __restrict__ partial, float* __restrict__ out)
{
    const int t = threadIdx.x;
    float v = partial[t];
    __shared__ float red[4];
    #pragma unroll
    for (int o = 32; o >= 1; o >>= 1) v += __shfl_xor(v, o, 64);
    if ((t & 63) == 0) red[t >> 6] = v;
    __syncthreads();
    if (t == 0) out[0] = red[0] + red[1] + red[2] + red[3];
}

extern "C" void kernel_launch(void* const* d_in, const int* in_sizes, int n_in,
                              void* d_out, int out_size, void* d_ws, size_t ws_size,
                              hipStream_t stream) {
    const float* im_set = (const float*)d_in[0];
    const float* s_seq  = (const float*)d_in[1];
    const int*   im_len = (const int*)d_in[2];
    const int*   s_len  = (const int*)d_in[3];
    float* out = (float*)d_out;

    char* ws = (char*)d_ws;
    const size_t imp_bytes = (size_t)NB * LI * DIM * 2;    // 18.9 MB (dense)
    const size_t sp_bytes  = (size_t)NB * LS * DIM * 2;    // 15.7 MB (dense)
    short* imp    = (short*)ws;
    short* sp     = (short*)(ws + imp_bytes);
    float* scores = (float*)(ws + imp_bytes + sp_bytes);   // 256 KB
    float* partial = (float*)(ws + imp_bytes + sp_bytes + (size_t)NB * NB * 4);

    // 256*36 + 256*30 = 16896 rows, one wave each -> 4224 blocks
    normalize_pack<<<4224, 256, 0, stream>>>(im_set, s_seq, imp, sp);

    dim3 grid(NB / 4, NB / 8);
    gemm_scores<<<grid, 256, 0, stream>>>(imp, sp, im_len, s_len, scores);

    loss_partial<<<64, 256, 0, stream>>>(scores, partial);
    loss_final<<<1, 256, 0, stream>>>(partial, out);
}

// Round 9
// 312.782 us; speedup vs baseline: 1.0824x; 1.0824x over previous
//
#include <hip/hip_runtime.h>
#include <hip/hip_bf16.h>

// AlignmentContrastiveLoss on MI355X.
// Pipeline:
//   K1 normalize_pack: fp32 L2-normalize rows of im_set/s_seq, drop CLS/special
//      tokens, cast to bf16. Both packed DENSE: im' [256][36][1024],
//      s' [256][30][1024].
//   K2 gemm_scores: bf16 MFMA GEMM per block: M=144 (4 images x 36),
//      N=240 (8 sentences x 30), K=1024. 4 waves, each owns 4 N-tiles
//      (wave 3: 3) x all 9 M-tiles. Schedule = the R2-verified 2-barrier
//      structure: BK=64, single-buffered LDS, stage -> syncthreads ->
//      compute -> syncthreads, NO fences/setprio/counted-vmcnt (R6-R8
//      post-mortems: fenced counted-vmcnt pipeline at this tile = 255 us vs
//      this structure's 150; compiler-scheduled 2-phase wins at 2 blocks/CU).
//      LDS geometry: row k-slice = 128-B line = 8 x 16-B chunks, XOR swizzle
//      phys_chunk = logical ^ (row&7) -- R1-R3 geometry, measured ZERO bank
//      conflicts. Both-sides rule: inverse-swizzled per-lane global source +
//      swizzled ds_read; LDS DMA dest linear.
//   K3 loss_partial + loss_final: contrastive loss, 64-block parallel.

typedef __attribute__((ext_vector_type(8))) short bf16x8;
typedef __attribute__((ext_vector_type(4))) float f32x4;

#define NB   256
#define DIM  1024
#define LI   36     // valid image regions (dense pack stride)
#define LS   30     // valid words (dense pack stride)
#define MT   9      // M-tiles per block (144 rows)
#define NT   15     // N-tiles per block (240 rows)

static __device__ inline ushort f2bf(float x) {
    union { __hip_bfloat16 h; ushort u; } cvt;
    cvt.h = __float2bfloat16(x);
    return cvt.u;
}

static __device__ __forceinline__ void gload_lds16(const void* g, void* l) {
    __builtin_amdgcn_global_load_lds(
        (const __attribute__((address_space(1))) void*)g,
        (__attribute__((address_space(3))) void*)l, 16, 0, 0);
}

// One wave per output row; every row is a real (valid) row.
__global__ __launch_bounds__(256) void normalize_pack(
    const float* __restrict__ im, const float* __restrict__ sq,
    short* __restrict__ imp, short* __restrict__ sp)
{
    const int gw   = (blockIdx.x * 256 + threadIdx.x) >> 6;
    const int lane = threadIdx.x & 63;
    const int NIM  = NB * LI;   // 9216 dense image rows

    const float* src;
    short* dst;
    if (gw < NIM) {
        int b = gw / LI, i = gw - b * LI;
        dst = imp + (size_t)gw * DIM;
        src = im + ((size_t)b * 37 + i + 1) * DIM;   // drop CLS region 0
    } else {
        int g2 = gw - NIM;
        int b = g2 / LS, j = g2 - b * LS;
        dst = sp + (size_t)g2 * DIM;
        src = sq + ((size_t)b * 33 + j + 1) * DIM;   // rows 1..30 of 33
    }

    const float4* s4 = (const float4*)src;
    float4 v[4];
    float ss = 0.f;
    #pragma unroll
    for (int t = 0; t < 4; ++t) {
        float4 x = s4[lane + 64 * t];
        v[t] = x;
        ss += x.x * x.x + x.y * x.y + x.z * x.z + x.w * x.w;
    }
    #pragma unroll
    for (int o = 32; o >= 1; o >>= 1) ss += __shfl_xor(ss, o, 64);
    float scale = 1.0f / fmaxf(sqrtf(ss), 1e-12f);
    ushort4* d4 = (ushort4*)dst;
    #pragma unroll
    for (int t = 0; t < 4; ++t) {
        float4 x = v[t];
        ushort4 o;
        o.x = f2bf(x.x * scale);
        o.y = f2bf(x.y * scale);
        o.z = f2bf(x.z * scale);
        o.w = f2bf(x.w * scale);
        d4[lane + 64 * t] = o;
    }
}

// Block: 256 threads = 4 waves. blockIdx.x -> 4 images (144 dense rows),
// blockIdx.y -> 8 sentences (240 dense rows). Wave w owns N-tiles 4w..4w+3
// (wave 3: tiles 12..14), all 9 M-tiles.
//
// LDS: As[144][64], Bs[240][64] bf16; a row's BK=64 k-slice = one 128-B line
// = 8 chunks of 16 B. Swizzle: phys_chunk = logical_chunk ^ (row & 7).
// Staging: one DMA instr = 1 KB = 8 rows. Lane i -> LDS linear
//   (row r0 + (i>>3), phys chunk i&7); global source logical chunk
//   (i&7)^(i>>3)  [r0 % 8 == 0]. Read side: tile row bases are multiples of
//   16 -> row&7 = l15&7 -> phys chunk = (g*4+q) ^ (l15&7), per-lane constant.
// Bank check: 8-consecutive-lane b128 groups touch 8 distinct chunks -> all
// 32 banks exactly once (reads and linear DMA writes) -> conflict-free
// (measured 0 in R1-R3).
__global__ __launch_bounds__(256, 2) void gemm_scores(
    const short* __restrict__ imp, const short* __restrict__ sp,
    const int* __restrict__ im_len, const int* __restrict__ s_len,
    float* __restrict__ scores)
{
    __shared__ short As[144 * 64];   // 18 KB
    __shared__ short Bs[240 * 64];   // 30 KB
    __shared__ float sred[4][4][3];  // [wave][img][sent-slot]

    const int tid  = threadIdx.x;
    const int wave = tid >> 6;
    const int lane = tid & 63;
    const int q    = lane >> 4;
    const int l15  = lane & 15;
    const int b0   = blockIdx.x * 4;
    const int c0   = blockIdx.y * 8;

    f32x4 acc[MT][4];
    #pragma unroll
    for (int mt = 0; mt < MT; ++mt)
        #pragma unroll
        for (int t = 0; t < 4; ++t)
            acc[mt][t] = (f32x4){0.f, 0.f, 0.f, 0.f};

    // Per-lane staging source offset: row (lane>>3) within the 8-row chunk,
    // inverse-swizzled 16-B chunk (lane&7)^(lane>>3).
    const int off_lane = ((lane >> 3) * 2048) + (((lane & 7) ^ (lane >> 3)) * 16);
    const char* baseA = (const char*)imp + (size_t)(b0 * LI) * 2048 + off_lane;
    const char* baseB = (const char*)sp  + (size_t)(c0 * LS) * 2048 + off_lane;

    // Read-side swizzled chunk byte offsets (per-lane constants).
    const int cs0 = ((q)     ^ (l15 & 7)) * 16;   // g = 0
    const int cs1 = ((4 + q) ^ (l15 & 7)) * 16;   // g = 1

    for (int k0 = 0; k0 < DIM; k0 += 64) {
        const int kb = k0 * 2;   // byte offset of this K-slice within a row
        // stage: A 18 chunks (8 rows / 1 KB each) + B 30 chunks = 48, 12/wave
        #pragma unroll
        for (int it = 0; it < 12; ++it) {
            const int cid = wave * 12 + it;          // wave-uniform
            if (cid < 18)
                gload_lds16(baseA + cid * (8 * 2048) + kb, (char*)As + cid * 1024);
            else
                gload_lds16(baseB + (cid - 18) * (8 * 2048) + kb, (char*)Bs + (cid - 18) * 1024);
        }
        __syncthreads();   // compiler emits vmcnt(0) drain for the DMA
        #pragma unroll
        for (int g = 0; g < 2; ++g) {
            const int cs = g ? cs1 : cs0;
            bf16x8 bfr[4];
            #pragma unroll
            for (int t = 0; t < 4; ++t) {
                const int nt = wave * 4 + t;
                if (nt < NT)   // wave-uniform
                    bfr[t] = *(const bf16x8*)((const char*)Bs + (nt * 16 + l15) * 128 + cs);
            }
            #pragma unroll
            for (int mt = 0; mt < MT; ++mt) {
                bf16x8 af = *(const bf16x8*)((const char*)As + (mt * 16 + l15) * 128 + cs);
                #pragma unroll
                for (int t = 0; t < 4; ++t)
                    if (wave * 4 + t < NT)
                        acc[mt][t] = __builtin_amdgcn_mfma_f32_16x16x32_bf16(
                            af, bfr[t], acc[mt][t], 0, 0, 0);
            }
        }
        __syncthreads();
    }

    // ---- Fused epilogue (verified R8, absmax 0) ----
    // C/D layout: lane holds col = l15, row = q*4 + r.
    // Packed A row g = mt*16 + q*4 + r; image = (4*mt+q)/9, region = g - 36*image.
    // Packed B col = nt*16 + l15; sentence sidx = col/30, word j = col - 30*sidx.
    int il[4];
    #pragma unroll
    for (int bb = 0; bb < 4; ++bb) il[bb] = im_len[b0 + bb] - 1;   // in [9, 36]

    // Wave w covers cols [64w, 64w+64) -> up to 3 sentences, base (64w)/30.
    const int sbase = (64 * wave) / 30;
    float part[4][3] = {{0.f,0.f,0.f},{0.f,0.f,0.f},{0.f,0.f,0.f},{0.f,0.f,0.f}};

    #pragma unroll
    for (int t = 0; t < 4; ++t) {
        const int nt = wave * 4 + t;
        if (nt >= NT) continue;                     // wave-uniform
        const int col  = nt * 16 + l15;             // 0..239
        const int sidx = col / 30;                  // per-lane sentence
        const int j    = col - 30 * sidx;           // word index
        const int sl2  = s_len[c0 + sidx] - 3;      // valid words, in [5, 30]
        const bool jv  = (j < sl2);
        const int s_begin = (nt * 16) / 30;         // wave-uniform
        const int s_end   = (nt * 16 + 15) / 30;

        #pragma unroll
        for (int bb = 0; bb < 4; ++bb) {
            const int ilb = il[bb];
            float m = -3.4e38f;
            #pragma unroll
            for (int mt = 0; mt < MT; ++mt) {
                const int im_lo = (4 * mt) / 9;          // compile-time
                const int im_hi = (4 * mt + 3) / 9;      // compile-time
                const int thr   = 9 * im_hi - 4 * mt;    // q >= thr -> im_hi
                #pragma unroll
                for (int r = 0; r < 4; ++r) {
                    const float v = acc[mt][t][r];
                    const int base = mt * 16 + q * 4 + r;
                    if (im_lo == im_hi) {
                        if (im_lo == bb) {
                            const int i = base - 36 * bb;
                            if (i < ilb) m = fmaxf(m, v);
                        }
                    } else {
                        const bool hi = (q >= thr);
                        if (!hi && im_lo == bb) {
                            const int i = base - 36 * bb;
                            if (i < ilb) m = fmaxf(m, v);
                        } else if (hi && im_hi == bb) {
                            const int i = base - 36 * bb;
                            if (i < ilb) m = fmaxf(m, v);
                        }
                    }
                }
            }
            // combine the 4 row-quads -> full max over image bb's regions
            m = fmaxf(m, __shfl_xor(m, 16, 64));
            m = fmaxf(m, __shfl_xor(m, 32, 64));
            // masked (zeroed) rows participate in the max only when il < 36
            if (ilb < LI) m = fmaxf(m, 0.f);
            const float c = (q == 0 && jv) ? m : 0.f;   // count each col once
            #pragma unroll
            for (int slot = 0; slot < 3; ++slot) {
                const int s = sbase + slot;
                if (s >= s_begin && s <= s_end) {        // wave-uniform
                    float v = (sidx == s) ? c : 0.f;
                    #pragma unroll
                    for (int off = 32; off >= 1; off >>= 1) v += __shfl_xor(v, off, 64);
                    part[bb][slot] += v;
                }
            }
        }
    }

    if (lane == 0) {
        #pragma unroll
        for (int bb = 0; bb < 4; ++bb)
            #pragma unroll
            for (int slot = 0; slot < 3; ++slot)
                sred[wave][bb][slot] = part[bb][slot];
    }
    __syncthreads();
    // 32 score cells: tid -> (bb = tid>>3, s = tid&7); sentence s gathers from
    // the waves whose 64-col window overlaps cols [30s, 30s+30).
    if (tid < 32) {
        const int bb = tid >> 3, s = tid & 7;
        float v = 0.f;
        #pragma unroll
        for (int w = 0; w < 4; ++w) {
            const int slot = s - (64 * w) / 30;
            if (slot >= 0 && slot < 3) v += sred[w][bb][slot];
        }
        scores[(b0 + bb) * NB + c0 + s] = v;
    }
}

// 64 blocks x 4 waves; wave handles row/col t of the score matrix.
__global__ __launch_bounds__(256) void loss_partial(
    const float* __restrict__ sc, float* __restrict__ partial)
{
    const int wave = threadIdx.x >> 6, lane = threadIdx.x & 63;
    const int t = blockIdx.x * 4 + wave;
    const float dt = sc[t * (NB + 1)];
    float rowmax = 0.f, colmax = 0.f;
    #pragma unroll
    for (int p = 0; p < 4; ++p) {
        const int k = lane + 64 * p;
        const float r = sc[t * NB + k];
        const float c = sc[k * NB + t];
        if (k != t) {
            rowmax = fmaxf(rowmax, 0.2f + r - dt);
            colmax = fmaxf(colmax, 0.2f + c - dt);
        }
    }
    #pragma unroll
    for (int o = 32; o >= 1; o >>= 1) {
        rowmax = fmaxf(rowmax, __shfl_xor(rowmax, o, 64));
        colmax = fmaxf(colmax, __shfl_xor(colmax, o, 64));
    }
    if (lane == 0) partial[t] = fmaxf(rowmax, 0.f) + fmaxf(colmax, 0.f);
}

__global__ __launch_bounds__(256) void loss_final(
    const float* __restrict__ partial, float* __restrict__ out)
{
    const int t = threadIdx.x;
    float v = partial[t];
    __shared__ float red[4];
    #pragma unroll
    for (int o = 32; o >= 1; o >>= 1) v += __shfl_xor(v, o, 64);
    if ((t & 63) == 0) red[t >> 6] = v;
    __syncthreads();
    if (t == 0) out[0] = red[0] + red[1] + red[2] + red[3];
}

extern "C" void kernel_launch(void* const* d_in, const int* in_sizes, int n_in,
                              void* d_out, int out_size, void* d_ws, size_t ws_size,
                              hipStream_t stream) {
    const float* im_set = (const float*)d_in[0];
    const float* s_seq  = (const float*)d_in[1];
    const int*   im_len = (const int*)d_in[2];
    const int*   s_len  = (const int*)d_in[3];
    float* out = (float*)d_out;

    char* ws = (char*)d_ws;
    const size_t imp_bytes = (size_t)NB * LI * DIM * 2;    // 18.9 MB (dense)
    const size_t sp_bytes  = (size_t)NB * LS * DIM * 2;    // 15.7 MB (dense)
    short* imp    = (short*)ws;
    short* sp     = (short*)(ws + imp_bytes);
    float* scores = (float*)(ws + imp_bytes + sp_bytes);   // 256 KB
    float* partial = (float*)(ws + imp_bytes + sp_bytes + (size_t)NB * NB * 4);

    // 256*36 + 256*30 = 16896 rows, one wave each -> 4224 blocks
    normalize_pack<<<4224, 256, 0, stream>>>(im_set, s_seq, imp, sp);

    dim3 grid(NB / 4, NB / 8);
    gemm_scores<<<grid, 256, 0, stream>>>(imp, sp, im_len, s_len, scores);

    loss_partial<<<64, 256, 0, stream>>>(scores, partial);
    loss_final<<<1, 256, 0, stream>>>(partial, out);
}

// Round 10
// 278.580 us; speedup vs baseline: 1.2153x; 1.1228x over previous
//
#include <hip/hip_runtime.h>
#include <hip/hip_bf16.h>

// AlignmentContrastiveLoss on MI355X.
// Pipeline:
//   K1 normalize_pack: fp32 L2-normalize rows of im_set/s_seq, drop CLS/special
//      tokens, cast to bf16. Both packed DENSE: im' [256][36][1024],
//      s' [256][30][1024].
//   K2 gemm_scores: bf16 MFMA GEMM per block: M=144 (4 images x 36),
//      N=240 (8 sentences x 30), K=1024. 4 waves, each owns 4 N-tiles x all
//      9 M-tiles. Schedule = R2's verified 2-barrier structure: BK=64,
//      single-buffered LDS, stage -> syncthreads -> compute -> syncthreads.
//      COMPUTE-LOOP FORM MATTERS (R9 post-mortem): af[9]+bfr[4] batched
//      upfront then an unbroken 36-MFMA register cluster = 46% MfmaUtil /
//      150 us (R2); per-mt {ds_read af; 4 MFMA} interleave = 26% / 229 us
//      (R9). Bs padded to 256 LDS rows so the cluster needs no NT guard
//      (wave 3 t=3 reads uninitialized LDS; its acc is never used).
//      LDS geometry: row k-slice = 128-B line = 8 x 16-B chunks, XOR swizzle
//      phys_chunk = logical ^ (row&7) -- measured ZERO bank conflicts.
//      Both-sides rule: inverse-swizzled per-lane global source + swizzled
//      ds_read; LDS DMA dest linear.
//   K3 loss_partial + loss_final: contrastive loss, 64-block parallel.

typedef __attribute__((ext_vector_type(8))) short bf16x8;
typedef __attribute__((ext_vector_type(4))) float f32x4;

#define NB   256
#define DIM  1024
#define LI   36     // valid image regions (dense pack stride)
#define LS   30     // valid words (dense pack stride)
#define MT   9      // M-tiles per block (144 rows)
#define NT   15     // N-tiles per block (240 valid cols)

static __device__ inline ushort f2bf(float x) {
    union { __hip_bfloat16 h; ushort u; } cvt;
    cvt.h = __float2bfloat16(x);
    return cvt.u;
}

static __device__ __forceinline__ void gload_lds16(const void* g, void* l) {
    __builtin_amdgcn_global_load_lds(
        (const __attribute__((address_space(1))) void*)g,
        (__attribute__((address_space(3))) void*)l, 16, 0, 0);
}

// One wave per output row; every row is a real (valid) row.
__global__ __launch_bounds__(256) void normalize_pack(
    const float* __restrict__ im, const float* __restrict__ sq,
    short* __restrict__ imp, short* __restrict__ sp)
{
    const int gw   = (blockIdx.x * 256 + threadIdx.x) >> 6;
    const int lane = threadIdx.x & 63;
    const int NIM  = NB * LI;   // 9216 dense image rows

    const float* src;
    short* dst;
    if (gw < NIM) {
        int b = gw / LI, i = gw - b * LI;
        dst = imp + (size_t)gw * DIM;
        src = im + ((size_t)b * 37 + i + 1) * DIM;   // drop CLS region 0
    } else {
        int g2 = gw - NIM;
        int b = g2 / LS, j = g2 - b * LS;
        dst = sp + (size_t)g2 * DIM;
        src = sq + ((size_t)b * 33 + j + 1) * DIM;   // rows 1..30 of 33
    }

    const float4* s4 = (const float4*)src;
    float4 v[4];
    float ss = 0.f;
    #pragma unroll
    for (int t = 0; t < 4; ++t) {
        float4 x = s4[lane + 64 * t];
        v[t] = x;
        ss += x.x * x.x + x.y * x.y + x.z * x.z + x.w * x.w;
    }
    #pragma unroll
    for (int o = 32; o >= 1; o >>= 1) ss += __shfl_xor(ss, o, 64);
    float scale = 1.0f / fmaxf(sqrtf(ss), 1e-12f);
    ushort4* d4 = (ushort4*)dst;
    #pragma unroll
    for (int t = 0; t < 4; ++t) {
        float4 x = v[t];
        ushort4 o;
        o.x = f2bf(x.x * scale);
        o.y = f2bf(x.y * scale);
        o.z = f2bf(x.z * scale);
        o.w = f2bf(x.w * scale);
        d4[lane + 64 * t] = o;
    }
}

// Block: 256 threads = 4 waves. blockIdx.x -> 4 images (144 dense rows),
// blockIdx.y -> 8 sentences (240 dense rows). Wave w owns N-tiles 4w..4w+3
// (wave 3's last tile is junk and unused), all 9 M-tiles.
//
// LDS: As[144][64], Bs[256][64] bf16 (B rows 240-255 never staged, only read
// into the unused wave3/t=3 fragment). A row's BK=64 k-slice = one 128-B
// line = 8 chunks of 16 B. Swizzle: phys_chunk = logical_chunk ^ (row & 7).
// Staging: one DMA instr = 1 KB = 8 rows. Lane i -> LDS linear
//   (row r0 + (i>>3), phys chunk i&7); global source logical chunk
//   (i&7)^(i>>3)  [r0 % 8 == 0]. Read side: tile row bases are multiples of
//   16 -> row&7 = l15&7 -> phys chunk = (g*4+q) ^ (l15&7), per-lane constant.
// Bank check: 8-consecutive-lane b128 groups touch 8 distinct chunks -> all
// 32 banks exactly once (reads and linear DMA writes) -> conflict-free
// (measured 0 in R1-R3, R9).
__global__ __launch_bounds__(256, 2) void gemm_scores(
    const short* __restrict__ imp, const short* __restrict__ sp,
    const int* __restrict__ im_len, const int* __restrict__ s_len,
    float* __restrict__ scores)
{
    __shared__ short As[144 * 64];   // 18 KB
    __shared__ short Bs[256 * 64];   // 32 KB (240 staged + 16 pad rows)
    __shared__ float sred[4][4][3];  // [wave][img][sent-slot]

    const int tid  = threadIdx.x;
    const int wave = tid >> 6;
    const int lane = tid & 63;
    const int q    = lane >> 4;
    const int l15  = lane & 15;
    const int b0   = blockIdx.x * 4;
    const int c0   = blockIdx.y * 8;

    f32x4 acc[MT][4];
    #pragma unroll
    for (int mt = 0; mt < MT; ++mt)
        #pragma unroll
        for (int t = 0; t < 4; ++t)
            acc[mt][t] = (f32x4){0.f, 0.f, 0.f, 0.f};

    // Per-lane staging source offset: row (lane>>3) within the 8-row chunk,
    // inverse-swizzled 16-B chunk (lane&7)^(lane>>3).
    const int off_lane = ((lane >> 3) * 2048) + (((lane & 7) ^ (lane >> 3)) * 16);
    const char* baseA = (const char*)imp + (size_t)(b0 * LI) * 2048 + off_lane;
    const char* baseB = (const char*)sp  + (size_t)(c0 * LS) * 2048 + off_lane;

    // Read-side swizzled chunk byte offsets (per-lane constants).
    const int cs0 = ((q)     ^ (l15 & 7)) * 16;   // g = 0
    const int cs1 = ((4 + q) ^ (l15 & 7)) * 16;   // g = 1

    for (int k0 = 0; k0 < DIM; k0 += 64) {
        const int kb = k0 * 2;   // byte offset of this K-slice within a row
        // stage: A 18 chunks + B 30 chunks (8 rows / 1 KB each), 12/wave mixed
        #pragma unroll
        for (int it = 0; it < 4; ++it) {
            const int cid = wave * 4 + it;                       // A 0..15
            gload_lds16(baseA + cid * (8 * 2048) + kb, (char*)As + cid * 1024);
        }
        if (wave >= 2) {
            const int cid = 14 + wave;                           // A 16,17
            gload_lds16(baseA + cid * (8 * 2048) + kb, (char*)As + cid * 1024);
        }
        #pragma unroll
        for (int it = 0; it < 7; ++it) {
            const int cid = wave * 7 + it;                       // B 0..27
            gload_lds16(baseB + cid * (8 * 2048) + kb, (char*)Bs + cid * 1024);
        }
        if (wave < 2) {
            const int cid = 28 + wave;                           // B 28,29
            gload_lds16(baseB + cid * (8 * 2048) + kb, (char*)Bs + cid * 1024);
        }
        __syncthreads();   // compiler emits vmcnt(0) drain for the DMA
        #pragma unroll
        for (int g = 0; g < 2; ++g) {
            const int cs = g ? cs1 : cs0;
            bf16x8 af[MT], bfr[4];
            #pragma unroll
            for (int mt = 0; mt < MT; ++mt)
                af[mt] = *(const bf16x8*)((const char*)As + (mt * 16 + l15) * 128 + cs);
            #pragma unroll
            for (int t = 0; t < 4; ++t)
                bfr[t] = *(const bf16x8*)((const char*)Bs + ((wave * 4 + t) * 16 + l15) * 128 + cs);
            #pragma unroll
            for (int mt = 0; mt < MT; ++mt)
                #pragma unroll
                for (int t = 0; t < 4; ++t)
                    acc[mt][t] = __builtin_amdgcn_mfma_f32_16x16x32_bf16(
                        af[mt], bfr[t], acc[mt][t], 0, 0, 0);
        }
        __syncthreads();
    }

    // ---- Fused epilogue (verified R8/R9, absmax 0) ----
    // C/D layout: lane holds col = l15, row = q*4 + r.
    // Packed A row g = mt*16 + q*4 + r; image = (4*mt+q)/9, region = g - 36*image.
    // Packed B col = nt*16 + l15; sentence sidx = col/30, word j = col - 30*sidx.
    int il[4];
    #pragma unroll
    for (int bb = 0; bb < 4; ++bb) il[bb] = im_len[b0 + bb] - 1;   // in [9, 36]

    // Wave w covers cols [64w, 64w+64) -> up to 3 sentences, base (64w)/30.
    const int sbase = (64 * wave) / 30;
    float part[4][3] = {{0.f,0.f,0.f},{0.f,0.f,0.f},{0.f,0.f,0.f},{0.f,0.f,0.f}};

    #pragma unroll
    for (int t = 0; t < 4; ++t) {
        const int nt = wave * 4 + t;
        if (nt >= NT) continue;                     // skips wave3 junk tile
        const int col  = nt * 16 + l15;             // 0..239
        const int sidx = col / 30;                  // per-lane sentence
        const int j    = col - 30 * sidx;           // word index
        const int sl2  = s_len[c0 + sidx] - 3;      // valid words, in [5, 30]
        const bool jv  = (j < sl2);
        const int s_begin = (nt * 16) / 30;         // wave-uniform
        const int s_end   = (nt * 16 + 15) / 30;

        #pragma unroll
        for (int bb = 0; bb < 4; ++bb) {
            const int ilb = il[bb];
            float m = -3.4e38f;
            #pragma unroll
            for (int mt = 0; mt < MT; ++mt) {
                const int im_lo = (4 * mt) / 9;          // compile-time
                const int im_hi = (4 * mt + 3) / 9;      // compile-time
                const int thr   = 9 * im_hi - 4 * mt;    // q >= thr -> im_hi
                #pragma unroll
                for (int r = 0; r < 4; ++r) {
                    const float v = acc[mt][t][r];
                    const int base = mt * 16 + q * 4 + r;
                    if (im_lo == im_hi) {
                        if (im_lo == bb) {
                            const int i = base - 36 * bb;
                            if (i < ilb) m = fmaxf(m, v);
                        }
                    } else {
                        const bool hi = (q >= thr);
                        if (!hi && im_lo == bb) {
                            const int i = base - 36 * bb;
                            if (i < ilb) m = fmaxf(m, v);
                        } else if (hi && im_hi == bb) {
                            const int i = base - 36 * bb;
                            if (i < ilb) m = fmaxf(m, v);
                        }
                    }
                }
            }
            // combine the 4 row-quads -> full max over image bb's regions
            m = fmaxf(m, __shfl_xor(m, 16, 64));
            m = fmaxf(m, __shfl_xor(m, 32, 64));
            // masked (zeroed) rows participate in the max only when il < 36
            if (ilb < LI) m = fmaxf(m, 0.f);
            const float c = (q == 0 && jv) ? m : 0.f;   // count each col once
            #pragma unroll
            for (int slot = 0; slot < 3; ++slot) {
                const int s = sbase + slot;
                if (s >= s_begin && s <= s_end) {        // wave-uniform
                    float v = (sidx == s) ? c : 0.f;
                    #pragma unroll
                    for (int off = 32; off >= 1; off >>= 1) v += __shfl_xor(v, off, 64);
                    part[bb][slot] += v;
                }
            }
        }
    }

    if (lane == 0) {
        #pragma unroll
        for (int bb = 0; bb < 4; ++bb)
            #pragma unroll
            for (int slot = 0; slot < 3; ++slot)
                sred[wave][bb][slot] = part[bb][slot];
    }
    __syncthreads();
    // 32 score cells: tid -> (bb = tid>>3, s = tid&7); sentence s gathers from
    // the waves whose 64-col window overlaps cols [30s, 30s+30).
    if (tid < 32) {
        const int bb = tid >> 3, s = tid & 7;
        float v = 0.f;
        #pragma unroll
        for (int w = 0; w < 4; ++w) {
            const int slot = s - (64 * w) / 30;
            if (slot >= 0 && slot < 3) v += sred[w][bb][slot];
        }
        scores[(b0 + bb) * NB + c0 + s] = v;
    }
}

// 64 blocks x 4 waves; wave handles row/col t of the score matrix.
__global__ __launch_bounds__(256) void loss_partial(
    const float* __restrict__ sc, float* __restrict__ partial)
{
    const int wave = threadIdx.x >> 6, lane = threadIdx.x & 63;
    const int t = blockIdx.x * 4 + wave;
    const float dt = sc[t * (NB + 1)];
    float rowmax = 0.f, colmax = 0.f;
    #pragma unroll
    for (int p = 0; p < 4; ++p) {
        const int k = lane + 64 * p;
        const float r = sc[t * NB + k];
        const float c = sc[k * NB + t];
        if (k != t) {
            rowmax = fmaxf(rowmax, 0.2f + r - dt);
            colmax = fmaxf(colmax, 0.2f + c - dt);
        }
    }
    #pragma unroll
    for (int o = 32; o >= 1; o >>= 1) {
        rowmax = fmaxf(rowmax, __shfl_xor(rowmax, o, 64));
        colmax = fmaxf(colmax, __shfl_xor(colmax, o, 64));
    }
    if (lane == 0) partial[t] = fmaxf(rowmax, 0.f) + fmaxf(colmax, 0.f);
}

__global__ __launch_bounds__(256) void loss_final(
    const float* __restrict__ partial, float* __restrict__ out)
{
    const int t = threadIdx.x;
    float v = partial[t];
    __shared__ float red[4];
    #pragma unroll
    for (int o = 32; o >= 1; o >>= 1) v += __shfl_xor(v, o, 64);
    if ((t & 63) == 0) red[t >> 6] = v;
    __syncthreads();
    if (t == 0) out[0] = red[0] + red[1] + red[2] + red[3];
}

extern "C" void kernel_launch(void* const* d_in, const int* in_sizes, int n_in,
                              void* d_out, int out_size, void* d_ws, size_t ws_size,
                              hipStream_t stream) {
    const float* im_set = (const float*)d_in[0];
    const float* s_seq  = (const float*)d_in[1];
    const int*   im_len = (const int*)d_in[2];
    const int*   s_len  = (const int*)d_in[3];
    float* out = (float*)d_out;

    char* ws = (char*)d_ws;
    const size_t imp_bytes = (size_t)NB * LI * DIM * 2;    // 18.9 MB (dense)
    const size_t sp_bytes  = (size_t)NB * LS * DIM * 2;    // 15.7 MB (dense)
    short* imp    = (short*)ws;
    short* sp     = (short*)(ws + imp_bytes);
    float* scores = (float*)(ws + imp_bytes + sp_bytes);   // 256 KB
    float* partial = (float*)(ws + imp_bytes + sp_bytes + (size_t)NB * NB * 4);

    // 256*36 + 256*30 = 16896 rows, one wave each -> 4224 blocks
    normalize_pack<<<4224, 256, 0, stream>>>(im_set, s_seq, imp, sp);

    dim3 grid(NB / 4, NB / 8);
    gemm_scores<<<grid, 256, 0, stream>>>(imp, sp, im_len, s_len, scores);

    loss_partial<<<64, 256, 0, stream>>>(scores, partial);
    loss_final<<<1, 256, 0, stream>>>(partial, out);
}

// Round 11
// 248.659 us; speedup vs baseline: 1.3615x; 1.1203x over previous
//
#include <hip/hip_runtime.h>
#include <hip/hip_bf16.h>

// AlignmentContrastiveLoss on MI355X.
// Consolidation of the best-measured variant of each component:
//   K1 normalize_pack: fp32 L2-normalize, drop CLS/special tokens, cast bf16.
//      A DENSE [256][36][1024]; B PADDED [256][32][1024] (30 valid + 2 zero
//      rows) -- tile-aligned B measured 150 us gemm vs dense-B's 181 (R10):
//      dense-B's 6% staging saving lost ~30 us of schedule overlap twice
//      (R9, R10). Tile-aligned wins.
//   K2 gemm_scores: the R2-verified kernel: M=144 (4 images x 36 dense),
//      N=256 (8 sentences x 32 padded), K=1024, BK=64, 4 waves, 2-barrier
//      single-buffer schedule, af[9]+bfr[4] batched ds_reads then an
//      unbroken 36-MFMA register cluster (46% MfmaUtil measured; per-mt
//      interleave measured 26%). LDS: 128-B row-lines, XOR chunk swizzle
//      phys = logical ^ (row&7), inverse-swizzled global_load_lds source +
//      swizzled ds_read (both-sides) -- measured ZERO bank conflicts.
//      Counted-vmcnt / triple-buffer pipelines measured SLOWER at this tile
//      (R8: 255 us) -- compiler-scheduled 2-phase wins at 2 blocks/CU.
//   K3 loss_partial + loss_final: contrastive loss, 64-block parallel.

typedef __attribute__((ext_vector_type(8))) short bf16x8;
typedef __attribute__((ext_vector_type(4))) float f32x4;

#define NB   256
#define DIM  1024
#define LI   36     // valid image regions (dense pack stride)
#define LIP  36     // A pack stride (dense)
#define LS   30     // valid words per sentence
#define LSP  32     // B pack stride (padded to 2 x 16)

static __device__ inline ushort f2bf(float x) {
    union { __hip_bfloat16 h; ushort u; } cvt;
    cvt.h = __float2bfloat16(x);
    return cvt.u;
}

static __device__ __forceinline__ void gload_lds16(const void* g, void* l) {
    __builtin_amdgcn_global_load_lds(
        (const __attribute__((address_space(1))) void*)g,
        (__attribute__((address_space(3))) void*)l, 16, 0, 0);
}

// One wave per output row. Rows 0..256*36-1 -> im' (dense); rest -> s'
// ([256][32], rows 30,31 of each sentence zeroed).
__global__ __launch_bounds__(256) void normalize_pack(
    const float* __restrict__ im, const float* __restrict__ sq,
    short* __restrict__ imp, short* __restrict__ sp)
{
    const int gw   = (blockIdx.x * 256 + threadIdx.x) >> 6;
    const int lane = threadIdx.x & 63;
    const int NIM  = NB * LI;   // 9216 dense image rows

    const float* src = nullptr;
    short* dst;
    if (gw < NIM) {
        int b = gw / LI, i = gw - b * LI;
        dst = imp + (size_t)gw * DIM;
        src = im + ((size_t)b * 37 + i + 1) * DIM;   // drop CLS region 0
    } else {
        int g2 = gw - NIM;                            // 0..8191
        int b = g2 >> 5, j = g2 & 31;
        dst = sp + (size_t)g2 * DIM;
        if (j < LS) src = sq + ((size_t)b * 33 + j + 1) * DIM;   // rows 1..30
    }

    if (src) {
        const float4* s4 = (const float4*)src;
        float4 v[4];
        float ss = 0.f;
        #pragma unroll
        for (int t = 0; t < 4; ++t) {
            float4 x = s4[lane + 64 * t];
            v[t] = x;
            ss += x.x * x.x + x.y * x.y + x.z * x.z + x.w * x.w;
        }
        #pragma unroll
        for (int o = 32; o >= 1; o >>= 1) ss += __shfl_xor(ss, o, 64);
        float scale = 1.0f / fmaxf(sqrtf(ss), 1e-12f);
        ushort4* d4 = (ushort4*)dst;
        #pragma unroll
        for (int t = 0; t < 4; ++t) {
            float4 x = v[t];
            ushort4 o;
            o.x = f2bf(x.x * scale);
            o.y = f2bf(x.y * scale);
            o.z = f2bf(x.z * scale);
            o.w = f2bf(x.w * scale);
            d4[lane + 64 * t] = o;
        }
    } else {
        // sentence pad row: zero (MFMA-safe; epilogue masks jv anyway)
        uint4 z = {0u, 0u, 0u, 0u};
        uint4* d4 = (uint4*)dst;
        d4[lane] = z;
        d4[lane + 64] = z;
    }
}

// Block: 256 threads = 4 waves. blockIdx.x -> 4 images (144 dense rows),
// blockIdx.y -> 8 sentences (256 padded rows). Wave w owns N-tiles 4w..4w+3
// (= sentences c0+2w, c0+2w+1), all 9 M-tiles -> score cells wave-private.
//
// LDS: As[144][64], Bs[256][64] bf16; a row's BK=64 k-slice = one 128-B line
// = 8 chunks of 16 B. Swizzle: phys_chunk = logical_chunk ^ (row & 7).
// Staging: one DMA instr = 1 KB = 8 rows; lane i -> row r0+(i>>3), phys
// chunk i&7; global source logical chunk (i&7)^(i>>3) [r0 % 8 == 0].
// Reads: tile row bases are multiples of 16 -> row&7 = l15&7 -> phys chunk
// = (g*4+q) ^ (l15&7), per-lane constant. 8-consecutive-lane b128 groups
// cover all 32 banks exactly once (reads and linear DMA writes) -> measured
// zero conflicts.
__global__ __launch_bounds__(256, 2) void gemm_scores(
    const short* __restrict__ imp, const short* __restrict__ sp,
    const int* __restrict__ im_len, const int* __restrict__ s_len,
    float* __restrict__ scores)
{
    __shared__ short As[144 * 64];   // 18 KB
    __shared__ short Bs[256 * 64];   // 32 KB

    const int tid  = threadIdx.x;
    const int wave = tid >> 6;
    const int lane = tid & 63;
    const int q    = lane >> 4;
    const int l15  = lane & 15;
    const int b0   = blockIdx.x * 4;
    const int c0   = blockIdx.y * 8;

    f32x4 acc[9][4];
    #pragma unroll
    for (int mt = 0; mt < 9; ++mt)
        #pragma unroll
        for (int t = 0; t < 4; ++t)
            acc[mt][t] = (f32x4){0.f, 0.f, 0.f, 0.f};

    // Per-lane staging source constants.
    const int srow   = lane >> 3;             // row within the 8-row chunk
    const int schunk = (lane & 7) ^ srow;     // inverse-swizzled 16B chunk
    const char* gA = (const char*)imp + (size_t)(b0 * LIP) * 2048
                     + srow * 2048 + schunk * 16;
    const char* gB = (const char*)sp + (size_t)(c0 * LSP) * 2048
                     + srow * 2048 + schunk * 16;

    // Read-side swizzled chunk byte offsets (per-lane constants).
    const int cs0 = ((q)     ^ (l15 & 7)) * 16;   // g = 0
    const int cs1 = ((4 + q) ^ (l15 & 7)) * 16;   // g = 1

    const int wa4 = wave * 4;   // A row-blocks: 18 total, 4/wave + 2 extra
    const int wb8 = wave * 8;   // B row-blocks: 32 total, 8/wave

    for (int k0 = 0; k0 < DIM; k0 += 64) {
        const int kb = k0 * 2;   // byte offset of this K-slice within a row
        // stage A: 144 rows x 128 B = 18 DMA instrs
        #pragma unroll
        for (int it = 0; it < 4; ++it) {
            const int rb = wa4 + it;
            gload_lds16(gA + rb * (8 * 2048) + kb, (char*)As + rb * 1024);
        }
        if (wave < 2) {
            const int rb = 16 + wave;
            gload_lds16(gA + rb * (8 * 2048) + kb, (char*)As + rb * 1024);
        }
        // stage B: 256 rows x 128 B = 32 DMA instrs, 8/wave
        #pragma unroll
        for (int it = 0; it < 8; ++it) {
            const int rb = wb8 + it;
            gload_lds16(gB + rb * (8 * 2048) + kb, (char*)Bs + rb * 1024);
        }
        __syncthreads();   // compiler emits vmcnt(0) drain for the DMA
        #pragma unroll
        for (int g = 0; g < 2; ++g) {
            const int cs = g ? cs1 : cs0;
            bf16x8 af[9], bfr[4];
            #pragma unroll
            for (int mt = 0; mt < 9; ++mt)
                af[mt] = *(const bf16x8*)((const char*)As + (mt * 16 + l15) * 128 + cs);
            #pragma unroll
            for (int t = 0; t < 4; ++t)
                bfr[t] = *(const bf16x8*)((const char*)Bs + ((wave * 4 + t) * 16 + l15) * 128 + cs);
            #pragma unroll
            for (int mt = 0; mt < 9; ++mt)
                #pragma unroll
                for (int t = 0; t < 4; ++t)
                    acc[mt][t] = __builtin_amdgcn_mfma_f32_16x16x32_bf16(
                        af[mt], bfr[t], acc[mt][t], 0, 0, 0);
        }
        __syncthreads();
    }

    // ---- Fused epilogue (R2-verified, absmax 0) ----
    // C/D layout: lane holds col = l15, row = q*4 + r.
    // Packed A row g = mt*16 + q*4 + r; image = (4*mt+q)/9 (compile-time
    // split; 36 = 4*9 so boundaries fall on q-quads), region = g - 36*image.
    // B col: tile-aligned -- sentence = c0 + (nt>>1), word jj = (nt&1)*16+l15.
    int il[4];
    #pragma unroll
    for (int bb = 0; bb < 4; ++bb) il[bb] = im_len[b0 + bb] - 1;   // in [9, 36]

    float sc[4][2] = {{0.f,0.f},{0.f,0.f},{0.f,0.f},{0.f,0.f}};
    #pragma unroll
    for (int t = 0; t < 4; ++t) {
        const int nt = wave * 4 + t;
        const int c  = c0 + (nt >> 1);
        const int sl = s_len[c] - 3;                 // valid words, in [5, 30]
        const int jj = (nt & 1) * 16 + l15;          // word index within sentence
        const bool jv = (jj < sl);

        float m[4] = {-3.4e38f, -3.4e38f, -3.4e38f, -3.4e38f};
        #pragma unroll
        for (int mt = 0; mt < 9; ++mt) {
            const int im_lo = (4 * mt) / 9;          // compile-time
            const int im_hi = (4 * mt + 3) / 9;      // compile-time
            const int thr   = 9 * im_hi - 4 * mt;    // q >= thr -> im_hi
            #pragma unroll
            for (int r = 0; r < 4; ++r) {
                const float v = acc[mt][t][r];
                const int base = mt * 16 + q * 4 + r;
                if (im_lo == im_hi) {
                    const int i = base - 36 * im_lo;
                    if (i < il[im_lo]) m[im_lo] = fmaxf(m[im_lo], v);
                } else {
                    const bool hi = (q >= thr);
                    if (!hi) {
                        const int i = base - 36 * im_lo;
                        if (i < il[im_lo]) m[im_lo] = fmaxf(m[im_lo], v);
                    } else {
                        const int i = base - 36 * im_hi;
                        if (i < il[im_hi]) m[im_hi] = fmaxf(m[im_hi], v);
                    }
                }
            }
        }
        #pragma unroll
        for (int bb = 0; bb < 4; ++bb) {
            float mm = m[bb];
            // combine the 4 row-quads -> full max over image bb's regions
            mm = fmaxf(mm, __shfl_xor(mm, 16, 64));
            mm = fmaxf(mm, __shfl_xor(mm, 32, 64));
            // masked (zeroed) entries participate in the max only when il < 36
            if (il[bb] < LI) mm = fmaxf(mm, 0.f);
            float v = (q == 0 && jv) ? mm : 0.f;     // count each column once
            #pragma unroll
            for (int off = 32; off >= 1; off >>= 1) v += __shfl_xor(v, off, 64);
            sc[bb][t >> 1] += v;
        }
    }
    if (lane == 0) {
        #pragma unroll
        for (int bb = 0; bb < 4; ++bb)
            #pragma unroll
            for (int h = 0; h < 2; ++h)
                scores[(b0 + bb) * NB + c0 + wave * 2 + h] = sc[bb][h];
    }
}

// 64 blocks x 4 waves; wave handles row/col t of the score matrix.
__global__ __launch_bounds__(256) void loss_partial(
    const float* __restrict__ sc, float* __restrict__ partial)
{
    const int wave = threadIdx.x >> 6, lane = threadIdx.x & 63;
    const int t = blockIdx.x * 4 + wave;
    const float dt = sc[t * (NB + 1)];
    float rowmax = 0.f, colmax = 0.f;
    #pragma unroll
    for (int p = 0; p < 4; ++p) {
        const int k = lane + 64 * p;
        const float r = sc[t * NB + k];
        const float c = sc[k * NB + t];
        if (k != t) {
            rowmax = fmaxf(rowmax, 0.2f + r - dt);
            colmax = fmaxf(colmax, 0.2f + c - dt);
        }
    }
    #pragma unroll
    for (int o = 32; o >= 1; o >>= 1) {
        rowmax = fmaxf(rowmax, __shfl_xor(rowmax, o, 64));
        colmax = fmaxf(colmax, __shfl_xor(colmax, o, 64));
    }
    if (lane == 0) partial[t] = fmaxf(rowmax, 0.f) + fmaxf(colmax, 0.f);
}

__global__ __launch_bounds__(256) void loss_final(
    const float* __restrict__ partial, float* __restrict__ out)
{
    const int t = threadIdx.x;
    float v = partial[t];
    __shared__ float red[4];
    #pragma unroll
    for (int o = 32; o >= 1; o >>= 1) v += __shfl_xor(v, o, 64);
    if ((t & 63) == 0) red[t >> 6] = v;
    __syncthreads();
    if (t == 0) out[0] = red[0] + red[1] + red[2] + red[3];
}

extern "C" void kernel_launch(void* const* d_in, const int* in_sizes, int n_in,
                              void* d_out, int out_size, void* d_ws, size_t ws_size,
                              hipStream_t stream) {
    const float* im_set = (const float*)d_in[0];
    const float* s_seq  = (const float*)d_in[1];
    const int*   im_len = (const int*)d_in[2];
    const int*   s_len  = (const int*)d_in[3];
    float* out = (float*)d_out;

    char* ws = (char*)d_ws;
    const size_t imp_bytes = (size_t)NB * LIP * DIM * 2;   // 18.9 MB (dense)
    const size_t sp_bytes  = (size_t)NB * LSP * DIM * 2;   // 16.8 MB (padded)
    short* imp    = (short*)ws;
    short* sp     = (short*)(ws + imp_bytes);
    float* scores = (float*)(ws + imp_bytes + sp_bytes);   // 256 KB
    float* partial = (float*)(ws + imp_bytes + sp_bytes + (size_t)NB * NB * 4);

    // 256*36 + 256*32 = 17408 rows, one wave each -> 4352 blocks
    normalize_pack<<<4352, 256, 0, stream>>>(im_set, s_seq, imp, sp);

    dim3 grid(NB / 4, NB / 8);
    gemm_scores<<<grid, 256, 0, stream>>>(imp, sp, im_len, s_len, scores);

    loss_partial<<<64, 256, 0, stream>>>(scores, partial);
    loss_final<<<1, 256, 0, stream>>>(partial, out);
}